// Round 4
// baseline (367.327 us; speedup 1.0000x reference)
//
#include <hip/hip_runtime.h>
#include <math.h>

#define NB 32
#define SLEN 8192
#define DIM 64
#define M 64
#define SEG 128
#define SPLITS 16
#define CHUNK 512   // rows per phase-B block
#define TILES 8     // CHUNK/64
#define FROWS 512   // rows per final block
#define FTILES 8    // FROWS/64

// ws layout (float offsets):
//  ql_s   [NB][M][DIM]            @ 0        (q_land * 1/sqrt(D), i.e. *0.125)
//  kl     [NB][M][DIM]            @ 131072
//  k2inv  [NB][M][M]              @ 262144   (pinv output V)
//  Wm     [NB][M][DIM]            @ 393216   (pinv scratch K2, then combine2's W)
//  k3     [NB][M][DIM]            @ 524288
//  den_p  [NB][SPLITS][M]         @ 655360
//  num_p  [NB][SPLITS][M][DIM]    @ 720896   (ends 2818048 floats = 11.3 MB)

// 16 fma: c[i][j] += a_i * bv[j]
#define ACC16(ax0, ax1, ax2, ax3, bv)                                          \
  c[0][0] = fmaf(ax0, bv.x, c[0][0]); c[0][1] = fmaf(ax0, bv.y, c[0][1]);      \
  c[0][2] = fmaf(ax0, bv.z, c[0][2]); c[0][3] = fmaf(ax0, bv.w, c[0][3]);      \
  c[1][0] = fmaf(ax1, bv.x, c[1][0]); c[1][1] = fmaf(ax1, bv.y, c[1][1]);      \
  c[1][2] = fmaf(ax1, bv.z, c[1][2]); c[1][3] = fmaf(ax1, bv.w, c[1][3]);      \
  c[2][0] = fmaf(ax2, bv.x, c[2][0]); c[2][1] = fmaf(ax2, bv.y, c[2][1]);      \
  c[2][2] = fmaf(ax2, bv.z, c[2][2]); c[2][3] = fmaf(ax2, bv.w, c[2][3]);      \
  c[3][0] = fmaf(ax3, bv.x, c[3][0]); c[3][1] = fmaf(ax3, bv.y, c[3][1]);      \
  c[3][2] = fmaf(ax3, bv.z, c[3][2]); c[3][3] = fmaf(ax3, bv.w, c[3][3]);

// c[i][j] += A[r0+i][kk] * B[kk][n0+j], kk over 64
__device__ __forceinline__ void mm_p1(const float* A, int lda, const float* B,
                                      int ldb, int r0, int n0, float (&c)[4][4]) {
  #pragma unroll 4
  for (int kk = 0; kk < 64; kk += 4) {
    float4 a0 = *(const float4*)(A + (r0 + 0) * lda + kk);
    float4 a1 = *(const float4*)(A + (r0 + 1) * lda + kk);
    float4 a2 = *(const float4*)(A + (r0 + 2) * lda + kk);
    float4 a3 = *(const float4*)(A + (r0 + 3) * lda + kk);
    float4 b0 = *(const float4*)(B + (kk + 0) * ldb + n0);
    float4 b1 = *(const float4*)(B + (kk + 1) * ldb + n0);
    float4 b2 = *(const float4*)(B + (kk + 2) * ldb + n0);
    float4 b3 = *(const float4*)(B + (kk + 3) * ldb + n0);
    ACC16(a0.x, a1.x, a2.x, a3.x, b0)
    ACC16(a0.y, a1.y, a2.y, a3.y, b1)
    ACC16(a0.z, a1.z, a2.z, a3.z, b2)
    ACC16(a0.w, a1.w, a2.w, a3.w, b3)
  }
}

// same, but B element (kk,n) transformed to (cd*I - B): fused Newton-Schulz step
__device__ __forceinline__ void mm_p1_tf(const float* A, int lda, const float* B,
                                         int ldb, float cd, int r0, int n0,
                                         float (&c)[4][4]) {
  #pragma unroll 4
  for (int kk = 0; kk < 64; kk += 4) {
    float4 a0 = *(const float4*)(A + (r0 + 0) * lda + kk);
    float4 a1 = *(const float4*)(A + (r0 + 1) * lda + kk);
    float4 a2 = *(const float4*)(A + (r0 + 2) * lda + kk);
    float4 a3 = *(const float4*)(A + (r0 + 3) * lda + kk);
    #pragma unroll
    for (int t = 0; t < 4; ++t) {
      float4 bb = *(const float4*)(B + (kk + t) * ldb + n0);
      int r = kk + t;
      bb.x = ((r == n0 + 0) ? cd : 0.f) - bb.x;
      bb.y = ((r == n0 + 1) ? cd : 0.f) - bb.y;
      bb.z = ((r == n0 + 2) ? cd : 0.f) - bb.z;
      bb.w = ((r == n0 + 3) ? cd : 0.f) - bb.w;
      float av0 = (t == 0) ? a0.x : (t == 1) ? a0.y : (t == 2) ? a0.z : a0.w;
      float av1 = (t == 0) ? a1.x : (t == 1) ? a1.y : (t == 2) ? a1.z : a1.w;
      float av2 = (t == 0) ? a2.x : (t == 1) ? a2.y : (t == 2) ? a2.z : a2.w;
      float av3 = (t == 0) ? a3.x : (t == 1) ? a3.y : (t == 2) ? a3.z : a3.w;
      ACC16(av0, av1, av2, av3, bb)
    }
  }
}

// outer-product accumulate: c[i][j] += A[s][m0+i] * B[s][n0+j], s over 64
__device__ __forceinline__ void mm_p2(const float* A, int lda, const float* B,
                                      int ldb, int m0, int n0, float (&c)[4][4]) {
  #pragma unroll 4
  for (int s = 0; s < 64; ++s) {
    float4 e = *(const float4*)(A + s * lda + m0);
    float4 vv = *(const float4*)(B + s * ldb + n0);
    ACC16(e.x, e.y, e.z, e.w, vv)
  }
}

// per-thread staging slice: rows srow+16i of a 64x64 tile, 16B per row
__device__ __forceinline__ void load_tile4(float4 (&dst)[4], const float* base,
                                           int t, int srow, int scol4) {
  #pragma unroll
  for (int i = 0; i < 4; ++i)
    dst[i] = *(const float4*)(base + (size_t)(t * 64 + srow + 16 * i) * DIM + scol4);
}
__device__ __forceinline__ void store_tile4(float* lds, const float4 (&src)[4],
                                            int srow, int scol4) {
  #pragma unroll
  for (int i = 0; i < 4; ++i)
    *(float4*)(lds + (srow + 16 * i) * 68 + scol4) = src[i];
}

// ---------------------------------------------------------------- pooling
__global__ __launch_bounds__(256) void pool_kernel(
    const float* __restrict__ q, const float* __restrict__ k,
    float* __restrict__ ql_s, float* __restrict__ kl) {
  int b = blockIdx.x >> 6, n = blockIdx.x & 63;
  int tid = threadIdx.x;
  int rg = tid >> 4, d4 = tid & 15;
  const float* qb = q + ((size_t)b * SLEN + (size_t)n * SEG) * DIM;
  const float* kb = k + ((size_t)b * SLEN + (size_t)n * SEG) * DIM;
  float4 aq = make_float4(0.f, 0.f, 0.f, 0.f);
  float4 ak = make_float4(0.f, 0.f, 0.f, 0.f);
  #pragma unroll
  for (int j = 0; j < 8; ++j) {
    int r = rg * 8 + j;
    float4 t = *(const float4*)(qb + r * DIM + 4 * d4);
    aq.x += t.x; aq.y += t.y; aq.z += t.z; aq.w += t.w;
    float4 u = *(const float4*)(kb + r * DIM + 4 * d4);
    ak.x += u.x; ak.y += u.y; ak.z += u.z; ak.w += u.w;
  }
  __shared__ float4 sq[256], sk[256];
  sq[tid] = aq; sk[tid] = ak;
  __syncthreads();
  #pragma unroll
  for (int off = 128; off >= 16; off >>= 1) {
    if (tid < off) {
      float4 a = sq[tid], bb = sq[tid + off];
      sq[tid] = make_float4(a.x + bb.x, a.y + bb.y, a.z + bb.z, a.w + bb.w);
      float4 c2 = sk[tid], d2 = sk[tid + off];
      sk[tid] = make_float4(c2.x + d2.x, c2.y + d2.y, c2.z + d2.z, c2.w + d2.w);
    }
    __syncthreads();
  }
  if (tid < 16) {
    float4 a = sq[tid], bb = sk[tid];
    size_t o = ((size_t)b * M + n) * DIM + 4 * tid;
    const float qs = 0.125f / 128.f, ks = 1.f / 128.f;
    *(float4*)(ql_s + o) = make_float4(a.x * qs, a.y * qs, a.z * qs, a.w * qs);
    *(float4*)(kl + o) = make_float4(bb.x * ks, bb.y * ks, bb.z * ks, bb.w * ks);
  }
}

// ---------------- phase B (kernel_3 split partials) + pinv, shared 53 KB LDS
__global__ __launch_bounds__(256) void phaseB_pinv_kernel(
    const float* __restrict__ k, const float* __restrict__ v,
    const float* __restrict__ ql_s, const float* __restrict__ klg,
    float* num_p, float* den_p, float* k2inv_g, float* k2_g) {
  __shared__ float smem[13312];  // 53248 B -> 3 blocks/CU
  int tid = threadIdx.x;
  int r0 = (tid >> 4) << 2, c0 = (tid & 15) << 2;
  int srow = tid >> 4, scol4 = (tid & 15) << 2;

  if (blockIdx.x >= NB) {
    // ---------------- phase B ----------------
    int blk = blockIdx.x - NB;
    int b = blk >> 4, sp = blk & 15;
    float* qlT = smem;            // [64 d][68 m]  (ql_s transposed)
    float* kv = smem + 4352;      // [64 s][68]    (k tile, then v tile)
    float* Es = smem + 8704;      // [64 s][68 m]
    float* dredF = smem + 13056;  // [4][64]

    #pragma unroll
    for (int i = 0; i < 16; ++i) {
      int e = tid + 256 * i;
      qlT[(e & 63) * 68 + (e >> 6)] = ql_s[(size_t)b * 4096 + e];
    }
    int m_den = tid & 63, qg = tid >> 6;
    float den_acc = 0.f;
    float cN[4][4];
    #pragma unroll
    for (int i = 0; i < 4; ++i)
      #pragma unroll
      for (int j = 0; j < 4; ++j) cN[i][j] = 0.f;

    const float* kbase = k + ((size_t)b * SLEN + (size_t)sp * CHUNK) * DIM;
    const float* vbase = v + ((size_t)b * SLEN + (size_t)sp * CHUNK) * DIM;

    float4 kreg[4], vreg[4];
    load_tile4(kreg, kbase, 0, srow, scol4);
    load_tile4(vreg, vbase, 0, srow, scol4);

    for (int sc = 0; sc < TILES; ++sc) {
      // write k tile (regs already loaded); prefetch next k
      store_tile4(kv, kreg, srow, scol4);
      if (sc < TILES - 1) load_tile4(kreg, kbase, sc + 1, srow, scol4);
      __syncthreads();  // A: k tile (and prologue qlT) visible
      // score GEMM: E[s][m] = exp(k[s] . ql_s[m])
      float c[4][4];
      #pragma unroll
      for (int i = 0; i < 4; ++i)
        #pragma unroll
        for (int j = 0; j < 4; ++j) c[i][j] = 0.f;
      mm_p1(kv, 68, qlT, 68, r0, c0, c);
      #pragma unroll
      for (int i = 0; i < 4; ++i)
        #pragma unroll
        for (int j = 0; j < 4; ++j) c[i][j] = __expf(c[i][j]);
      __syncthreads();  // B: k reads done
      // write v tile over kv; write E; prefetch next v
      store_tile4(kv, vreg, srow, scol4);
      #pragma unroll
      for (int i = 0; i < 4; ++i)
        *(float4*)(Es + (r0 + i) * 68 + c0) =
            make_float4(c[i][0], c[i][1], c[i][2], c[i][3]);
      if (sc < TILES - 1) load_tile4(vreg, vbase, sc + 1, srow, scol4);
      __syncthreads();  // C: v + E visible
      // den partial + num outer product
      #pragma unroll
      for (int t = 0; t < 16; ++t) den_acc += Es[(qg * 16 + t) * 68 + m_den];
      mm_p2(Es, 68, kv, 68, r0, c0, cN);
      __syncthreads();  // D: Es/kv reads done before next overwrite
    }
    dredF[qg * 64 + m_den] = den_acc;
    __syncthreads();
    if (tid < 64)
      den_p[((size_t)b * SPLITS + sp) * 64 + tid] =
          dredF[tid] + dredF[64 + tid] + dredF[128 + tid] + dredF[192 + tid];
    float* np = num_p + ((size_t)b * SPLITS + sp) * 4096;
    #pragma unroll
    for (int i = 0; i < 4; ++i)
      *(float4*)(np + (size_t)(r0 + i) * 64 + c0) =
          make_float4(cN[i][0], cN[i][1], cN[i][2], cN[i][3]);
  } else {
    // ---------------- pinv (3 buffers; K2 kept in global) ----------------
    int b = blockIdx.x;
    float* b1 = smem;            // ql rows, then V
    float* b2 = smem + 4352;     // klT, then A1=K*V
    float* b3 = smem + 8704;     // rowsum partials, K2 copy, then NS temp
    float* red = smem + 13056;   // [64+]
    float* k2b = k2_g + (size_t)b * 4096;

    #pragma unroll
    for (int i = 0; i < 4; ++i) {
      int idx = tid + 256 * i;
      int s = idx >> 4, j = idx & 15;
      *(float4*)(b1 + s * 68 + 4 * j) =
          *(const float4*)(ql_s + (size_t)b * 4096 + (size_t)s * 64 + 4 * j);
    }
    #pragma unroll
    for (int i = 0; i < 16; ++i) {
      int e = tid + 256 * i;
      b2[(e & 63) * 68 + (e >> 6)] = klg[(size_t)b * 4096 + e];
    }
    __syncthreads();
    // kernel_2 scores
    float c[4][4];
    #pragma unroll
    for (int i = 0; i < 4; ++i)
      #pragma unroll
      for (int j = 0; j < 4; ++j) c[i][j] = 0.f;
    mm_p1(b1, 68, b2, 68, r0, c0, c);
    #pragma unroll
    for (int i = 0; i < 4; ++i) {
      float pr = 0.f;
      #pragma unroll
      for (int j = 0; j < 4; ++j) { c[i][j] = __expf(c[i][j]); pr += c[i][j]; }
      b3[(r0 + i) * 16 + (tid & 15)] = pr;
    }
    __syncthreads();
    if (tid < 64) {
      float rs = 0.f;
      #pragma unroll
      for (int g = 0; g < 16; ++g) rs += b3[tid * 16 + g];
      red[tid] = 1.f / rs;
    }
    __syncthreads();
    // normalize -> K2 (global + LDS b3)
    #pragma unroll
    for (int i = 0; i < 4; ++i) {
      float inv = red[r0 + i];
      #pragma unroll
      for (int j = 0; j < 4; ++j) c[i][j] *= inv;
      float4 val = make_float4(c[i][0], c[i][1], c[i][2], c[i][3]);
      *(float4*)(k2b + (size_t)(r0 + i) * 64 + c0) = val;
      *(float4*)(b3 + (r0 + i) * 68 + c0) = val;
    }
    __syncthreads();
    // init scale: 1/max_m colsum
    if (tid < 64) {
      float cs = 0.f;
      #pragma unroll 8
      for (int n2 = 0; n2 < 64; ++n2) cs += b3[n2 * 68 + tid];
      float mx = cs;
      #pragma unroll
      for (int off = 1; off < 64; off <<= 1) mx = fmaxf(mx, __shfl_xor(mx, off));
      red[0] = 1.f / mx;
    }
    __syncthreads();
    float iscale = red[0];
    // V = iscale * K2^T -> b1 (ql dead)
    #pragma unroll
    for (int i = 0; i < 16; ++i) {
      int e = tid + 256 * i;
      int r = e >> 6, cc = e & 63;
      b1[r * 68 + cc] = b3[cc * 68 + r] * iscale;
    }
    __syncthreads();

    for (int it = 0; it < 6; ++it) {
      // A1 = K2 @ V -> b2
      #pragma unroll
      for (int i = 0; i < 4; ++i)
        #pragma unroll
        for (int j = 0; j < 4; ++j) c[i][j] = 0.f;
      mm_p1(k2b, 64, b1, 68, r0, c0, c);
      #pragma unroll
      for (int i = 0; i < 4; ++i)
        *(float4*)(b2 + (r0 + i) * 68 + c0) =
            make_float4(c[i][0], c[i][1], c[i][2], c[i][3]);
      __syncthreads();
      // T = A1 @ (7I - A1) -> b3
      #pragma unroll
      for (int i = 0; i < 4; ++i)
        #pragma unroll
        for (int j = 0; j < 4; ++j) c[i][j] = 0.f;
      mm_p1_tf(b2, 68, b2, 68, 7.f, r0, c0, c);
      #pragma unroll
      for (int i = 0; i < 4; ++i)
        *(float4*)(b3 + (r0 + i) * 68 + c0) =
            make_float4(c[i][0], c[i][1], c[i][2], c[i][3]);
      __syncthreads();
      // R = A1 @ (15I - T) -> b3 in place (barrier before write)
      #pragma unroll
      for (int i = 0; i < 4; ++i)
        #pragma unroll
        for (int j = 0; j < 4; ++j) c[i][j] = 0.f;
      mm_p1_tf(b2, 68, b3, 68, 15.f, r0, c0, c);
      __syncthreads();
      #pragma unroll
      for (int i = 0; i < 4; ++i)
        *(float4*)(b3 + (r0 + i) * 68 + c0) =
            make_float4(c[i][0], c[i][1], c[i][2], c[i][3]);
      __syncthreads();
      // V = 0.25 * V @ (13I - R) -> b1 in place
      #pragma unroll
      for (int i = 0; i < 4; ++i)
        #pragma unroll
        for (int j = 0; j < 4; ++j) c[i][j] = 0.f;
      mm_p1_tf(b1, 68, b3, 68, 13.f, r0, c0, c);
      __syncthreads();
      #pragma unroll
      for (int i = 0; i < 4; ++i)
        *(float4*)(b1 + (r0 + i) * 68 + c0) = make_float4(
            0.25f * c[i][0], 0.25f * c[i][1], 0.25f * c[i][2], 0.25f * c[i][3]);
      __syncthreads();
    }
    #pragma unroll
    for (int i = 0; i < 16; ++i) {
      int e = tid + 256 * i;
      k2inv_g[(size_t)b * 4096 + e] = b1[(e >> 6) * 68 + (e & 63)];
    }
  }
}

// ------------------------------------------------ reduce split partials -> k3
__global__ __launch_bounds__(256) void combine1_kernel(
    const float* __restrict__ num_p, const float* __restrict__ den_p,
    float* __restrict__ k3) {
  int b = blockIdx.x >> 3, slice = blockIdx.x & 7;
  int tid = threadIdx.x;
  int e0 = slice * 512 + tid * 2;
  float a0 = 0.f, a1 = 0.f;
  for (int sp = 0; sp < SPLITS; ++sp) {
    float2 t = *(const float2*)(num_p + ((size_t)b * SPLITS + sp) * 4096 + e0);
    a0 += t.x; a1 += t.y;
  }
  int m = e0 >> 6;
  float dsum = 0.f;
  for (int sp = 0; sp < SPLITS; ++sp)
    dsum += den_p[((size_t)b * SPLITS + sp) * 64 + m];
  float dinv = 1.f / dsum;
  *(float2*)(k3 + (size_t)b * 4096 + e0) = make_float2(a0 * dinv, a1 * dinv);
}

// ------------------------------------------------------ W = k2inv @ k3
__global__ __launch_bounds__(256) void combine2_kernel(
    const float* __restrict__ k2inv, const float* __restrict__ k3,
    float* __restrict__ Wm) {
  __shared__ float A[4352], Bm[4352];
  int b = blockIdx.x, tid = threadIdx.x;
  int r0 = (tid >> 4) << 2, c0 = (tid & 15) << 2;
  #pragma unroll
  for (int i = 0; i < 4; ++i) {
    int idx = tid + 256 * i;
    int s = idx >> 4, j = idx & 15;
    *(float4*)(A + s * 68 + 4 * j) =
        *(const float4*)(k2inv + (size_t)b * 4096 + (size_t)s * 64 + 4 * j);
    *(float4*)(Bm + s * 68 + 4 * j) =
        *(const float4*)(k3 + (size_t)b * 4096 + (size_t)s * 64 + 4 * j);
  }
  __syncthreads();
  float c[4][4];
  #pragma unroll
  for (int i = 0; i < 4; ++i)
    #pragma unroll
    for (int j = 0; j < 4; ++j) c[i][j] = 0.f;
  mm_p1(A, 68, Bm, 68, r0, c0, c);
  #pragma unroll
  for (int i = 0; i < 4; ++i)
    *(float4*)(Wm + (size_t)b * 4096 + (size_t)(r0 + i) * 64 + c0) =
        make_float4(c[i][0], c[i][1], c[i][2], c[i][3]);
}

// --------------------------- final: x = softmax(q*scale @ kl^T) @ W, fused
// Row ownership: group g (tids 16g..16g+15, one wave) reads q rows 4g..4g+3 as
// the scores A-operand and overwrites exactly those rows with E -> no barrier
// between E-write and the out-GEMM (same-wave, in-order DS). den via shfl_xor.
__global__ __launch_bounds__(256) void final_kernel(
    const float* __restrict__ q, const float* __restrict__ klg,
    const float* __restrict__ Wm, float* __restrict__ out) {
  __shared__ float smem[12800];  // 51200 B -> 3 blocks/CU
  float* klT = smem;             // [64 d][68 m]
  float* Wl = smem + 4352;       // [64 m][64 d]
  float* Es = smem + 8448;       // q tile, then E tile [64 r][68]
  int b = blockIdx.x >> 4, rb = blockIdx.x & 15;
  int tid = threadIdx.x;
  int r0 = (tid >> 4) << 2, c0 = (tid & 15) << 2;
  int srow = tid >> 4, scol4 = (tid & 15) << 2;

  #pragma unroll
  for (int i = 0; i < 16; ++i) {
    int e = tid + 256 * i;
    klT[(e & 63) * 68 + (e >> 6)] = klg[(size_t)b * 4096 + e];
  }
  #pragma unroll
  for (int i = 0; i < 4; ++i) {
    int idx = tid + 256 * i;
    *(float4*)(Wl + idx * 4) = *(const float4*)(Wm + (size_t)b * 4096 + idx * 4);
  }

  const float* qbase = q + ((size_t)b * SLEN + (size_t)rb * FROWS) * DIM;
  float* obase = out + ((size_t)b * SLEN + (size_t)rb * FROWS) * DIM;
  float4 qreg[4];
  load_tile4(qreg, qbase, 0, srow, scol4);

  for (int sc = 0; sc < FTILES; ++sc) {
    // stage q tile (scaled); prefetch next
    #pragma unroll
    for (int i = 0; i < 4; ++i) {
      float4 t = qreg[i];
      *(float4*)(Es + (srow + 16 * i) * 68 + scol4) =
          make_float4(t.x * 0.125f, t.y * 0.125f, t.z * 0.125f, t.w * 0.125f);
    }
    if (sc < FTILES - 1) load_tile4(qreg, qbase, sc + 1, srow, scol4);
    __syncthreads();  // A: q tile (and prologue klT/Wl) visible
    // scores
    float c[4][4];
    #pragma unroll
    for (int i = 0; i < 4; ++i)
      #pragma unroll
      for (int j = 0; j < 4; ++j) c[i][j] = 0.f;
    mm_p1(Es, 68, klT, 68, r0, c0, c);
    #pragma unroll
    for (int i = 0; i < 4; ++i)
      #pragma unroll
      for (int j = 0; j < 4; ++j) c[i][j] = __expf(c[i][j]);
    // row denominators: 16-lane group shuffle reduce (no LDS, no barrier)
    float inv[4];
    #pragma unroll
    for (int i = 0; i < 4; ++i) {
      float s = (c[i][0] + c[i][1]) + (c[i][2] + c[i][3]);
      s += __shfl_xor(s, 1);
      s += __shfl_xor(s, 2);
      s += __shfl_xor(s, 4);
      s += __shfl_xor(s, 8);
      inv[i] = 1.f / s;
    }
    // write E over own q rows (same-wave rows; no barrier needed)
    #pragma unroll
    for (int i = 0; i < 4; ++i)
      *(float4*)(Es + (r0 + i) * 68 + c0) =
          make_float4(c[i][0], c[i][1], c[i][2], c[i][3]);
    // out = (E @ W) * inv
    float c3[4][4];
    #pragma unroll
    for (int i = 0; i < 4; ++i)
      #pragma unroll
      for (int j = 0; j < 4; ++j) c3[i][j] = 0.f;
    mm_p1(Es, 68, Wl, 64, r0, c0, c3);
    #pragma unroll
    for (int i = 0; i < 4; ++i)
      *(float4*)(obase + (size_t)(sc * 64 + r0 + i) * 64 + c0) = make_float4(
          c3[i][0] * inv[i], c3[i][1] * inv[i], c3[i][2] * inv[i],
          c3[i][3] * inv[i]);
    __syncthreads();  // C: Es reads done before next stage-write
  }
}

// ----------------------------------------------------------------- launcher
extern "C" void kernel_launch(void* const* d_in, const int* in_sizes, int n_in,
                              void* d_out, int out_size, void* d_ws, size_t ws_size,
                              hipStream_t stream) {
  (void)in_sizes; (void)n_in; (void)out_size; (void)ws_size;
  const float* q = (const float*)d_in[0];
  const float* k = (const float*)d_in[1];
  const float* v = (const float*)d_in[2];
  float* out = (float*)d_out;
  float* ws = (float*)d_ws;

  float* ql_s = ws;
  float* kl = ws + 131072;
  float* k2inv = ws + 262144;
  float* Wm = ws + 393216;  // pinv K2 scratch, then combine2 output
  float* k3 = ws + 524288;
  float* den_p = ws + 655360;
  float* num_p = ws + 720896;

  pool_kernel<<<NB * 64, 256, 0, stream>>>(q, k, ql_s, kl);
  // pinv blocks 0..31 dispatch first and run concurrently with phase B
  phaseB_pinv_kernel<<<NB + NB * SPLITS, 256, 0, stream>>>(
      k, v, ql_s, kl, num_p, den_p, k2inv, Wm);
  combine1_kernel<<<NB * 8, 256, 0, stream>>>(num_p, den_p, k3);
  combine2_kernel<<<NB, 256, 0, stream>>>(k2inv, k3, Wm);
  final_kernel<<<NB * 16, 256, 0, stream>>>(q, kl, Wm, out);
}

// Round 5
// 351.593 us; speedup vs baseline: 1.0447x; 1.0447x over previous
//
#include <hip/hip_runtime.h>
#include <math.h>

#define NB 32
#define SLEN 8192
#define DIM 64
#define M 64
#define SEG 128
#define SPLITS 32
#define CHUNK 256   // rows per phase-B block
#define TILES 4     // CHUNK/64
#define FROWS 256   // rows per final block
#define FTILES 4    // FROWS/64

// ws layout (float offsets):
//  ql_s   [NB][M][DIM]            @ 0        (q_land * 1/sqrt(D), i.e. *0.125)
//  kl     [NB][M][DIM]            @ 131072
//  k2inv  [NB][M][M]              @ 262144   (pinv output V)
//  Wm     [NB][M][DIM]            @ 393216   (pinv scratch K2, then combine2's W)
//  k3     [NB][M][DIM]            @ 524288
//  den_p  [NB][SPLITS][M]         @ 655360
//  num_p  [NB][SPLITS][M][DIM]    @ 720896   (ends 4915200 floats = 19.7 MB)

// 16 fma: c[i][j] += a_i * bv[j]
#define ACC16(ax0, ax1, ax2, ax3, bv)                                          \
  c[0][0] = fmaf(ax0, bv.x, c[0][0]); c[0][1] = fmaf(ax0, bv.y, c[0][1]);      \
  c[0][2] = fmaf(ax0, bv.z, c[0][2]); c[0][3] = fmaf(ax0, bv.w, c[0][3]);      \
  c[1][0] = fmaf(ax1, bv.x, c[1][0]); c[1][1] = fmaf(ax1, bv.y, c[1][1]);      \
  c[1][2] = fmaf(ax1, bv.z, c[1][2]); c[1][3] = fmaf(ax1, bv.w, c[1][3]);      \
  c[2][0] = fmaf(ax2, bv.x, c[2][0]); c[2][1] = fmaf(ax2, bv.y, c[2][1]);      \
  c[2][2] = fmaf(ax2, bv.z, c[2][2]); c[2][3] = fmaf(ax2, bv.w, c[2][3]);      \
  c[3][0] = fmaf(ax3, bv.x, c[3][0]); c[3][1] = fmaf(ax3, bv.y, c[3][1]);      \
  c[3][2] = fmaf(ax3, bv.z, c[3][2]); c[3][3] = fmaf(ax3, bv.w, c[3][3]);

// c[i][j] += A[r0+i][kk] * B[kk][n0+j], kk over 64
__device__ __forceinline__ void mm_p1(const float* A, int lda, const float* B,
                                      int ldb, int r0, int n0, float (&c)[4][4]) {
  #pragma unroll 4
  for (int kk = 0; kk < 64; kk += 4) {
    float4 a0 = *(const float4*)(A + (r0 + 0) * lda + kk);
    float4 a1 = *(const float4*)(A + (r0 + 1) * lda + kk);
    float4 a2 = *(const float4*)(A + (r0 + 2) * lda + kk);
    float4 a3 = *(const float4*)(A + (r0 + 3) * lda + kk);
    float4 b0 = *(const float4*)(B + (kk + 0) * ldb + n0);
    float4 b1 = *(const float4*)(B + (kk + 1) * ldb + n0);
    float4 b2 = *(const float4*)(B + (kk + 2) * ldb + n0);
    float4 b3 = *(const float4*)(B + (kk + 3) * ldb + n0);
    ACC16(a0.x, a1.x, a2.x, a3.x, b0)
    ACC16(a0.y, a1.y, a2.y, a3.y, b1)
    ACC16(a0.z, a1.z, a2.z, a3.z, b2)
    ACC16(a0.w, a1.w, a2.w, a3.w, b3)
  }
}

// same, but B element (kk,n) transformed to (cd*I - B): fused Newton-Schulz step
__device__ __forceinline__ void mm_p1_tf(const float* A, int lda, const float* B,
                                         int ldb, float cd, int r0, int n0,
                                         float (&c)[4][4]) {
  #pragma unroll 4
  for (int kk = 0; kk < 64; kk += 4) {
    float4 a0 = *(const float4*)(A + (r0 + 0) * lda + kk);
    float4 a1 = *(const float4*)(A + (r0 + 1) * lda + kk);
    float4 a2 = *(const float4*)(A + (r0 + 2) * lda + kk);
    float4 a3 = *(const float4*)(A + (r0 + 3) * lda + kk);
    #pragma unroll
    for (int t = 0; t < 4; ++t) {
      float4 bb = *(const float4*)(B + (kk + t) * ldb + n0);
      int r = kk + t;
      bb.x = ((r == n0 + 0) ? cd : 0.f) - bb.x;
      bb.y = ((r == n0 + 1) ? cd : 0.f) - bb.y;
      bb.z = ((r == n0 + 2) ? cd : 0.f) - bb.z;
      bb.w = ((r == n0 + 3) ? cd : 0.f) - bb.w;
      float av0 = (t == 0) ? a0.x : (t == 1) ? a0.y : (t == 2) ? a0.z : a0.w;
      float av1 = (t == 0) ? a1.x : (t == 1) ? a1.y : (t == 2) ? a1.z : a1.w;
      float av2 = (t == 0) ? a2.x : (t == 1) ? a2.y : (t == 2) ? a2.z : a2.w;
      float av3 = (t == 0) ? a3.x : (t == 1) ? a3.y : (t == 2) ? a3.z : a3.w;
      ACC16(av0, av1, av2, av3, bb)
    }
  }
}

// outer-product accumulate: c[i][j] += A[s][m0+i] * B[s][n0+j], s over 64
__device__ __forceinline__ void mm_p2(const float* A, int lda, const float* B,
                                      int ldb, int m0, int n0, float (&c)[4][4]) {
  #pragma unroll 4
  for (int s = 0; s < 64; ++s) {
    float4 e = *(const float4*)(A + s * lda + m0);
    float4 vv = *(const float4*)(B + s * ldb + n0);
    ACC16(e.x, e.y, e.z, e.w, vv)
  }
}

// per-thread staging slice: rows srow+16i of a 64x64 tile, 16B per row
__device__ __forceinline__ void load_tile4(float4 (&dst)[4], const float* base,
                                           int t, int srow, int scol4) {
  #pragma unroll
  for (int i = 0; i < 4; ++i)
    dst[i] = *(const float4*)(base + (size_t)(t * 64 + srow + 16 * i) * DIM + scol4);
}
__device__ __forceinline__ void store_tile4(float* lds, const float4 (&src)[4],
                                            int srow, int scol4) {
  #pragma unroll
  for (int i = 0; i < 4; ++i)
    *(float4*)(lds + (srow + 16 * i) * 68 + scol4) = src[i];
}

// ---------------------------------------------------------------- pooling
__global__ __launch_bounds__(256) void pool_kernel(
    const float* __restrict__ q, const float* __restrict__ k,
    float* __restrict__ ql_s, float* __restrict__ kl) {
  int b = blockIdx.x >> 6, n = blockIdx.x & 63;
  int tid = threadIdx.x;
  int rg = tid >> 4, d4 = tid & 15;
  const float* qb = q + ((size_t)b * SLEN + (size_t)n * SEG) * DIM;
  const float* kb = k + ((size_t)b * SLEN + (size_t)n * SEG) * DIM;
  float4 aq = make_float4(0.f, 0.f, 0.f, 0.f);
  float4 ak = make_float4(0.f, 0.f, 0.f, 0.f);
  #pragma unroll
  for (int j = 0; j < 8; ++j) {
    int r = rg * 8 + j;
    float4 t = *(const float4*)(qb + r * DIM + 4 * d4);
    aq.x += t.x; aq.y += t.y; aq.z += t.z; aq.w += t.w;
    float4 u = *(const float4*)(kb + r * DIM + 4 * d4);
    ak.x += u.x; ak.y += u.y; ak.z += u.z; ak.w += u.w;
  }
  __shared__ float4 sq[256], sk[256];
  sq[tid] = aq; sk[tid] = ak;
  __syncthreads();
  #pragma unroll
  for (int off = 128; off >= 16; off >>= 1) {
    if (tid < off) {
      float4 a = sq[tid], bb = sq[tid + off];
      sq[tid] = make_float4(a.x + bb.x, a.y + bb.y, a.z + bb.z, a.w + bb.w);
      float4 c2 = sk[tid], d2 = sk[tid + off];
      sk[tid] = make_float4(c2.x + d2.x, c2.y + d2.y, c2.z + d2.z, c2.w + d2.w);
    }
    __syncthreads();
  }
  if (tid < 16) {
    float4 a = sq[tid], bb = sk[tid];
    size_t o = ((size_t)b * M + n) * DIM + 4 * tid;
    const float qs = 0.125f / 128.f, ks = 1.f / 128.f;
    *(float4*)(ql_s + o) = make_float4(a.x * qs, a.y * qs, a.z * qs, a.w * qs);
    *(float4*)(kl + o) = make_float4(bb.x * ks, bb.y * ks, bb.z * ks, bb.w * ks);
  }
}

// ---------------- phase B (kernel_3 split partials) + pinv, shared 53 KB LDS
__global__ __launch_bounds__(256) void phaseB_pinv_kernel(
    const float* __restrict__ k, const float* __restrict__ v,
    const float* __restrict__ ql_s, const float* __restrict__ klg,
    float* num_p, float* den_p, float* k2inv_g, float* k2_g) {
  __shared__ float smem[13312];  // 53248 B -> 3 blocks/CU
  int tid = threadIdx.x;
  int r0 = (tid >> 4) << 2, c0 = (tid & 15) << 2;
  int srow = tid >> 4, scol4 = (tid & 15) << 2;

  if (blockIdx.x >= NB) {
    // ---------------- phase B ----------------
    int blk = blockIdx.x - NB;
    int b = blk >> 5, sp = blk & 31;
    float* qlT = smem;            // [64 d][68 m]  (ql_s transposed)
    float* kv = smem + 4352;      // [64 s][68]    (k tile, then v tile)
    float* Es = smem + 8704;      // [64 s][68 m]
    float* dredF = smem + 13056;  // [4][64]

    #pragma unroll
    for (int i = 0; i < 16; ++i) {
      int e = tid + 256 * i;
      qlT[(e & 63) * 68 + (e >> 6)] = ql_s[(size_t)b * 4096 + e];
    }
    int m_den = tid & 63, qg = tid >> 6;
    float den_acc = 0.f;
    float cN[4][4];
    #pragma unroll
    for (int i = 0; i < 4; ++i)
      #pragma unroll
      for (int j = 0; j < 4; ++j) cN[i][j] = 0.f;

    const float* kbase = k + ((size_t)b * SLEN + (size_t)sp * CHUNK) * DIM;
    const float* vbase = v + ((size_t)b * SLEN + (size_t)sp * CHUNK) * DIM;

    // prologue prefetch: k first, then v (so k-use waits vmcnt(4), not 0)
    float4 kr[4], vr[4];
    load_tile4(kr, kbase, 0, srow, scol4);
    load_tile4(vr, vbase, 0, srow, scol4);

    // fully unrolled: straight-line SSA -> prefetch regs don't cross a
    // dynamic back-edge (the round-4 spill pattern)
    #pragma unroll
    for (int sc = 0; sc < TILES; ++sc) {
      store_tile4(kv, kr, srow, scol4);  // waits only on k loads
      __syncthreads();  // A: k tile (and prologue qlT) visible
      // score GEMM: E[s][m] = exp(k[s] . ql_s[m])
      float c[4][4];
      #pragma unroll
      for (int i = 0; i < 4; ++i)
        #pragma unroll
        for (int j = 0; j < 4; ++j) c[i][j] = 0.f;
      mm_p1(kv, 68, qlT, 68, r0, c0, c);
      #pragma unroll
      for (int i = 0; i < 4; ++i)
        #pragma unroll
        for (int j = 0; j < 4; ++j) c[i][j] = __expf(c[i][j]);
      __syncthreads();  // B: k reads done
      // v tile (arrived under the GEMM) over kv; write E
      store_tile4(kv, vr, srow, scol4);
      #pragma unroll
      for (int i = 0; i < 4; ++i)
        *(float4*)(Es + (r0 + i) * 68 + c0) =
            make_float4(c[i][0], c[i][1], c[i][2], c[i][3]);
      // prefetch NEXT k/v here: den+PV (~1500 cyc) covers the HBM latency
      if (sc < TILES - 1) {
        load_tile4(kr, kbase, sc + 1, srow, scol4);
        load_tile4(vr, vbase, sc + 1, srow, scol4);
      }
      __syncthreads();  // C: v + E visible
      // den partial + num outer product
      #pragma unroll
      for (int t = 0; t < 16; ++t) den_acc += Es[(qg * 16 + t) * 68 + m_den];
      mm_p2(Es, 68, kv, 68, r0, c0, cN);
      __syncthreads();  // D: Es/kv reads done before next overwrite
    }
    dredF[qg * 64 + m_den] = den_acc;
    __syncthreads();
    if (tid < 64)
      den_p[((size_t)b * SPLITS + sp) * 64 + tid] =
          dredF[tid] + dredF[64 + tid] + dredF[128 + tid] + dredF[192 + tid];
    float* np = num_p + ((size_t)b * SPLITS + sp) * 4096;
    #pragma unroll
    for (int i = 0; i < 4; ++i)
      *(float4*)(np + (size_t)(r0 + i) * 64 + c0) =
          make_float4(cN[i][0], cN[i][1], cN[i][2], cN[i][3]);
  } else {
    // ---------------- pinv (3 buffers; K2 kept in global) ----------------
    int b = blockIdx.x;
    float* b1 = smem;            // ql rows, then V
    float* b2 = smem + 4352;     // klT, then A1=K*V
    float* b3 = smem + 8704;     // rowsum partials, K2 copy, then NS temp
    float* red = smem + 13056;   // [64+]
    float* k2b = k2_g + (size_t)b * 4096;

    #pragma unroll
    for (int i = 0; i < 4; ++i) {
      int idx = tid + 256 * i;
      int s = idx >> 4, j = idx & 15;
      *(float4*)(b1 + s * 68 + 4 * j) =
          *(const float4*)(ql_s + (size_t)b * 4096 + (size_t)s * 64 + 4 * j);
    }
    #pragma unroll
    for (int i = 0; i < 16; ++i) {
      int e = tid + 256 * i;
      b2[(e & 63) * 68 + (e >> 6)] = klg[(size_t)b * 4096 + e];
    }
    __syncthreads();
    // kernel_2 scores
    float c[4][4];
    #pragma unroll
    for (int i = 0; i < 4; ++i)
      #pragma unroll
      for (int j = 0; j < 4; ++j) c[i][j] = 0.f;
    mm_p1(b1, 68, b2, 68, r0, c0, c);
    #pragma unroll
    for (int i = 0; i < 4; ++i) {
      float pr = 0.f;
      #pragma unroll
      for (int j = 0; j < 4; ++j) { c[i][j] = __expf(c[i][j]); pr += c[i][j]; }
      b3[(r0 + i) * 16 + (tid & 15)] = pr;
    }
    __syncthreads();
    if (tid < 64) {
      float rs = 0.f;
      #pragma unroll
      for (int g = 0; g < 16; ++g) rs += b3[tid * 16 + g];
      red[tid] = 1.f / rs;
    }
    __syncthreads();
    // normalize -> K2 (global + LDS b3)
    #pragma unroll
    for (int i = 0; i < 4; ++i) {
      float inv = red[r0 + i];
      #pragma unroll
      for (int j = 0; j < 4; ++j) c[i][j] *= inv;
      float4 val = make_float4(c[i][0], c[i][1], c[i][2], c[i][3]);
      *(float4*)(k2b + (size_t)(r0 + i) * 64 + c0) = val;
      *(float4*)(b3 + (r0 + i) * 68 + c0) = val;
    }
    __syncthreads();
    // init scale: 1/max_m colsum
    if (tid < 64) {
      float cs = 0.f;
      #pragma unroll 8
      for (int n2 = 0; n2 < 64; ++n2) cs += b3[n2 * 68 + tid];
      float mx = cs;
      #pragma unroll
      for (int off = 1; off < 64; off <<= 1) mx = fmaxf(mx, __shfl_xor(mx, off));
      red[0] = 1.f / mx;
    }
    __syncthreads();
    float iscale = red[0];
    // V = iscale * K2^T -> b1 (ql dead)
    #pragma unroll
    for (int i = 0; i < 16; ++i) {
      int e = tid + 256 * i;
      int r = e >> 6, cc = e & 63;
      b1[r * 68 + cc] = b3[cc * 68 + r] * iscale;
    }
    __syncthreads();

    for (int it = 0; it < 6; ++it) {
      // A1 = K2 @ V -> b2
      #pragma unroll
      for (int i = 0; i < 4; ++i)
        #pragma unroll
        for (int j = 0; j < 4; ++j) c[i][j] = 0.f;
      mm_p1(k2b, 64, b1, 68, r0, c0, c);
      #pragma unroll
      for (int i = 0; i < 4; ++i)
        *(float4*)(b2 + (r0 + i) * 68 + c0) =
            make_float4(c[i][0], c[i][1], c[i][2], c[i][3]);
      __syncthreads();
      // T = A1 @ (7I - A1) -> b3
      #pragma unroll
      for (int i = 0; i < 4; ++i)
        #pragma unroll
        for (int j = 0; j < 4; ++j) c[i][j] = 0.f;
      mm_p1_tf(b2, 68, b2, 68, 7.f, r0, c0, c);
      #pragma unroll
      for (int i = 0; i < 4; ++i)
        *(float4*)(b3 + (r0 + i) * 68 + c0) =
            make_float4(c[i][0], c[i][1], c[i][2], c[i][3]);
      __syncthreads();
      // R = A1 @ (15I - T) -> b3 in place (barrier before write)
      #pragma unroll
      for (int i = 0; i < 4; ++i)
        #pragma unroll
        for (int j = 0; j < 4; ++j) c[i][j] = 0.f;
      mm_p1_tf(b2, 68, b3, 68, 15.f, r0, c0, c);
      __syncthreads();
      #pragma unroll
      for (int i = 0; i < 4; ++i)
        *(float4*)(b3 + (r0 + i) * 68 + c0) =
            make_float4(c[i][0], c[i][1], c[i][2], c[i][3]);
      __syncthreads();
      // V = 0.25 * V @ (13I - R) -> b1 in place
      #pragma unroll
      for (int i = 0; i < 4; ++i)
        #pragma unroll
        for (int j = 0; j < 4; ++j) c[i][j] = 0.f;
      mm_p1_tf(b1, 68, b3, 68, 13.f, r0, c0, c);
      __syncthreads();
      #pragma unroll
      for (int i = 0; i < 4; ++i)
        *(float4*)(b1 + (r0 + i) * 68 + c0) = make_float4(
            0.25f * c[i][0], 0.25f * c[i][1], 0.25f * c[i][2], 0.25f * c[i][3]);
      __syncthreads();
    }
    #pragma unroll
    for (int i = 0; i < 16; ++i) {
      int e = tid + 256 * i;
      k2inv_g[(size_t)b * 4096 + e] = b1[(e >> 6) * 68 + (e & 63)];
    }
  }
}

// ------------------------------------------------ reduce split partials -> k3
__global__ __launch_bounds__(256) void combine1_kernel(
    const float* __restrict__ num_p, const float* __restrict__ den_p,
    float* __restrict__ k3) {
  int b = blockIdx.x >> 3, slice = blockIdx.x & 7;
  int tid = threadIdx.x;
  int e0 = slice * 512 + tid * 2;
  float a0 = 0.f, a1 = 0.f;
  for (int sp = 0; sp < SPLITS; ++sp) {
    float2 t = *(const float2*)(num_p + ((size_t)b * SPLITS + sp) * 4096 + e0);
    a0 += t.x; a1 += t.y;
  }
  int m = e0 >> 6;
  float dsum = 0.f;
  for (int sp = 0; sp < SPLITS; ++sp)
    dsum += den_p[((size_t)b * SPLITS + sp) * 64 + m];
  float dinv = 1.f / dsum;
  *(float2*)(k3 + (size_t)b * 4096 + e0) = make_float2(a0 * dinv, a1 * dinv);
}

// ------------------------------------------------------ W = k2inv @ k3
__global__ __launch_bounds__(256) void combine2_kernel(
    const float* __restrict__ k2inv, const float* __restrict__ k3,
    float* __restrict__ Wm) {
  __shared__ float A[4352], Bm[4352];
  int b = blockIdx.x, tid = threadIdx.x;
  int r0 = (tid >> 4) << 2, c0 = (tid & 15) << 2;
  #pragma unroll
  for (int i = 0; i < 4; ++i) {
    int idx = tid + 256 * i;
    int s = idx >> 4, j = idx & 15;
    *(float4*)(A + s * 68 + 4 * j) =
        *(const float4*)(k2inv + (size_t)b * 4096 + (size_t)s * 64 + 4 * j);
    *(float4*)(Bm + s * 68 + 4 * j) =
        *(const float4*)(k3 + (size_t)b * 4096 + (size_t)s * 64 + 4 * j);
  }
  __syncthreads();
  float c[4][4];
  #pragma unroll
  for (int i = 0; i < 4; ++i)
    #pragma unroll
    for (int j = 0; j < 4; ++j) c[i][j] = 0.f;
  mm_p1(A, 68, Bm, 68, r0, c0, c);
  #pragma unroll
  for (int i = 0; i < 4; ++i)
    *(float4*)(Wm + (size_t)b * 4096 + (size_t)(r0 + i) * 64 + c0) =
        make_float4(c[i][0], c[i][1], c[i][2], c[i][3]);
}

// --------------------------- final: x = softmax(q*scale @ kl^T) @ W, fused
// Row ownership: group g (tids 16g..16g+15) reads q rows 4g..4g+3 as the
// scores A-operand and overwrites exactly those rows with E -> no barrier
// between E-write and the out-GEMM (same-wave, in-order DS). den via shfl_xor.
__global__ __launch_bounds__(256) void final_kernel(
    const float* __restrict__ q, const float* __restrict__ klg,
    const float* __restrict__ Wm, float* __restrict__ out) {
  __shared__ float smem[12800];  // 51200 B -> 3 blocks/CU
  float* klT = smem;             // [64 d][68 m]
  float* Wl = smem + 4352;       // [64 m][64 d]
  float* Es = smem + 8448;       // q tile, then E tile [64 r][68]
  int b = blockIdx.x >> 5, rb = blockIdx.x & 31;
  int tid = threadIdx.x;
  int r0 = (tid >> 4) << 2, c0 = (tid & 15) << 2;
  int srow = tid >> 4, scol4 = (tid & 15) << 2;

  #pragma unroll
  for (int i = 0; i < 16; ++i) {
    int e = tid + 256 * i;
    klT[(e & 63) * 68 + (e >> 6)] = klg[(size_t)b * 4096 + e];
  }
  #pragma unroll
  for (int i = 0; i < 4; ++i) {
    int idx = tid + 256 * i;
    *(float4*)(Wl + idx * 4) = *(const float4*)(Wm + (size_t)b * 4096 + idx * 4);
  }

  const float* qbase = q + ((size_t)b * SLEN + (size_t)rb * FROWS) * DIM;
  float* obase = out + ((size_t)b * SLEN + (size_t)rb * FROWS) * DIM;
  float4 qr[4];
  load_tile4(qr, qbase, 0, srow, scol4);

  #pragma unroll
  for (int sc = 0; sc < FTILES; ++sc) {
    // stage q tile (scaled)
    #pragma unroll
    for (int i = 0; i < 4; ++i) {
      float4 t = qr[i];
      *(float4*)(Es + (srow + 16 * i) * 68 + scol4) =
          make_float4(t.x * 0.125f, t.y * 0.125f, t.z * 0.125f, t.w * 0.125f);
    }
    __syncthreads();  // A: q tile (and prologue klT/Wl) visible
    // scores
    float c[4][4];
    #pragma unroll
    for (int i = 0; i < 4; ++i)
      #pragma unroll
      for (int j = 0; j < 4; ++j) c[i][j] = 0.f;
    mm_p1(Es, 68, klT, 68, r0, c0, c);
    #pragma unroll
    for (int i = 0; i < 4; ++i)
      #pragma unroll
      for (int j = 0; j < 4; ++j) c[i][j] = __expf(c[i][j]);
    // row denominators: 16-lane group shuffle reduce (no LDS, no barrier)
    float inv[4];
    #pragma unroll
    for (int i = 0; i < 4; ++i) {
      float s = (c[i][0] + c[i][1]) + (c[i][2] + c[i][3]);
      s += __shfl_xor(s, 1);
      s += __shfl_xor(s, 2);
      s += __shfl_xor(s, 4);
      s += __shfl_xor(s, 8);
      inv[i] = 1.f / s;
    }
    // write E over own q rows (same-wave rows; no barrier needed)
    #pragma unroll
    for (int i = 0; i < 4; ++i)
      *(float4*)(Es + (r0 + i) * 68 + c0) =
          make_float4(c[i][0], c[i][1], c[i][2], c[i][3]);
    // prefetch next q tile: out-GEMM (~1024 fma) covers the HBM latency
    if (sc < FTILES - 1) load_tile4(qr, qbase, sc + 1, srow, scol4);
    // out = (E @ W) * inv
    float c3[4][4];
    #pragma unroll
    for (int i = 0; i < 4; ++i)
      #pragma unroll
      for (int j = 0; j < 4; ++j) c3[i][j] = 0.f;
    mm_p1(Es, 68, Wl, 64, r0, c0, c3);
    #pragma unroll
    for (int i = 0; i < 4; ++i)
      *(float4*)(obase + (size_t)(sc * 64 + r0 + i) * 64 + c0) = make_float4(
          c3[i][0] * inv[i], c3[i][1] * inv[i], c3[i][2] * inv[i],
          c3[i][3] * inv[i]);
    __syncthreads();  // C: Es reads done before next stage-write
  }
}

// ----------------------------------------------------------------- launcher
extern "C" void kernel_launch(void* const* d_in, const int* in_sizes, int n_in,
                              void* d_out, int out_size, void* d_ws, size_t ws_size,
                              hipStream_t stream) {
  (void)in_sizes; (void)n_in; (void)out_size; (void)ws_size;
  const float* q = (const float*)d_in[0];
  const float* k = (const float*)d_in[1];
  const float* v = (const float*)d_in[2];
  float* out = (float*)d_out;
  float* ws = (float*)d_ws;

  float* ql_s = ws;
  float* kl = ws + 131072;
  float* k2inv = ws + 262144;
  float* Wm = ws + 393216;  // pinv K2 scratch, then combine2 output
  float* k3 = ws + 524288;
  float* den_p = ws + 655360;
  float* num_p = ws + 720896;

  pool_kernel<<<NB * 64, 256, 0, stream>>>(q, k, ql_s, kl);
  // pinv blocks 0..31 dispatch first and run concurrently with phase B
  phaseB_pinv_kernel<<<NB + NB * SPLITS, 256, 0, stream>>>(
      k, v, ql_s, kl, num_p, den_p, k2inv, Wm);
  combine1_kernel<<<NB * 8, 256, 0, stream>>>(num_p, den_p, k3);
  combine2_kernel<<<NB, 256, 0, stream>>>(k2inv, k3, Wm);
  final_kernel<<<NB * 32, 256, 0, stream>>>(q, kl, Wm, out);
}

// Round 6
// 350.787 us; speedup vs baseline: 1.0471x; 1.0023x over previous
//
#include <hip/hip_runtime.h>
#include <math.h>

#define NB 32
#define SLEN 8192
#define DIM 64
#define M 64
#define SEG 128
#define SPLITS 32
#define CHUNK 256   // rows per phase-B block
#define TILES 4     // CHUNK/64
#define FROWS 256   // rows per final block
#define FTILES 4    // FROWS/64

// ws layout (float offsets):
//  ql_s   [NB][M][DIM]            @ 0        (q_land * 1/sqrt(D), i.e. *0.125)
//  kl     [NB][M][DIM]            @ 131072
//  k2inv  [NB][M][M]              @ 262144   (pinv output V)
//  Wm     [NB][M][DIM]            @ 393216   (pinv scratch K2, then combine2's W)
//  k3     [NB][M][DIM]            @ 524288
//  den_p  [NB][SPLITS][M]         @ 655360
//  num_p  [NB][SPLITS][M][DIM]    @ 720896   (ends 4915200 floats = 19.7 MB)

// 16 fma: c[i][j] += a_i * bv[j]
#define ACC16(ax0, ax1, ax2, ax3, bv)                                          \
  c[0][0] = fmaf(ax0, bv.x, c[0][0]); c[0][1] = fmaf(ax0, bv.y, c[0][1]);      \
  c[0][2] = fmaf(ax0, bv.z, c[0][2]); c[0][3] = fmaf(ax0, bv.w, c[0][3]);      \
  c[1][0] = fmaf(ax1, bv.x, c[1][0]); c[1][1] = fmaf(ax1, bv.y, c[1][1]);      \
  c[1][2] = fmaf(ax1, bv.z, c[1][2]); c[1][3] = fmaf(ax1, bv.w, c[1][3]);      \
  c[2][0] = fmaf(ax2, bv.x, c[2][0]); c[2][1] = fmaf(ax2, bv.y, c[2][1]);      \
  c[2][2] = fmaf(ax2, bv.z, c[2][2]); c[2][3] = fmaf(ax2, bv.w, c[2][3]);      \
  c[3][0] = fmaf(ax3, bv.x, c[3][0]); c[3][1] = fmaf(ax3, bv.y, c[3][1]);      \
  c[3][2] = fmaf(ax3, bv.z, c[3][2]); c[3][3] = fmaf(ax3, bv.w, c[3][3]);

// c[i][j] += A[r0+i][kk] * B[kk][n0+j], kk over 64
__device__ __forceinline__ void mm_p1(const float* A, int lda, const float* B,
                                      int ldb, int r0, int n0, float (&c)[4][4]) {
  #pragma unroll 4
  for (int kk = 0; kk < 64; kk += 4) {
    float4 a0 = *(const float4*)(A + (r0 + 0) * lda + kk);
    float4 a1 = *(const float4*)(A + (r0 + 1) * lda + kk);
    float4 a2 = *(const float4*)(A + (r0 + 2) * lda + kk);
    float4 a3 = *(const float4*)(A + (r0 + 3) * lda + kk);
    float4 b0 = *(const float4*)(B + (kk + 0) * ldb + n0);
    float4 b1 = *(const float4*)(B + (kk + 1) * ldb + n0);
    float4 b2 = *(const float4*)(B + (kk + 2) * ldb + n0);
    float4 b3 = *(const float4*)(B + (kk + 3) * ldb + n0);
    ACC16(a0.x, a1.x, a2.x, a3.x, b0)
    ACC16(a0.y, a1.y, a2.y, a3.y, b1)
    ACC16(a0.z, a1.z, a2.z, a3.z, b2)
    ACC16(a0.w, a1.w, a2.w, a3.w, b3)
  }
}

// same, but B element (kk,n) transformed to (cd*I - B): fused Newton-Schulz step
__device__ __forceinline__ void mm_p1_tf(const float* A, int lda, const float* B,
                                         int ldb, float cd, int r0, int n0,
                                         float (&c)[4][4]) {
  #pragma unroll 4
  for (int kk = 0; kk < 64; kk += 4) {
    float4 a0 = *(const float4*)(A + (r0 + 0) * lda + kk);
    float4 a1 = *(const float4*)(A + (r0 + 1) * lda + kk);
    float4 a2 = *(const float4*)(A + (r0 + 2) * lda + kk);
    float4 a3 = *(const float4*)(A + (r0 + 3) * lda + kk);
    #pragma unroll
    for (int t = 0; t < 4; ++t) {
      float4 bb = *(const float4*)(B + (kk + t) * ldb + n0);
      int r = kk + t;
      bb.x = ((r == n0 + 0) ? cd : 0.f) - bb.x;
      bb.y = ((r == n0 + 1) ? cd : 0.f) - bb.y;
      bb.z = ((r == n0 + 2) ? cd : 0.f) - bb.z;
      bb.w = ((r == n0 + 3) ? cd : 0.f) - bb.w;
      float av0 = (t == 0) ? a0.x : (t == 1) ? a0.y : (t == 2) ? a0.z : a0.w;
      float av1 = (t == 0) ? a1.x : (t == 1) ? a1.y : (t == 2) ? a1.z : a1.w;
      float av2 = (t == 0) ? a2.x : (t == 1) ? a2.y : (t == 2) ? a2.z : a2.w;
      float av3 = (t == 0) ? a3.x : (t == 1) ? a3.y : (t == 2) ? a3.z : a3.w;
      ACC16(av0, av1, av2, av3, bb)
    }
  }
}

// outer-product accumulate: c[i][j] += A[s][m0+i] * B[s][n0+j], s over 64
__device__ __forceinline__ void mm_p2(const float* A, int lda, const float* B,
                                      int ldb, int m0, int n0, float (&c)[4][4]) {
  #pragma unroll 4
  for (int s = 0; s < 64; ++s) {
    float4 e = *(const float4*)(A + s * lda + m0);
    float4 vv = *(const float4*)(B + s * ldb + n0);
    ACC16(e.x, e.y, e.z, e.w, vv)
  }
}

// ---- named-member tile registers: no arrays => SROA-safe (r5 spill fix) ----
struct T4 { float4 a, b, c, d; };

__device__ __forceinline__ T4 load_t4(const float* base, int t, int srow,
                                      int scol4) {
  T4 r;
  r.a = *(const float4*)(base + (size_t)(t * 64 + srow +  0) * DIM + scol4);
  r.b = *(const float4*)(base + (size_t)(t * 64 + srow + 16) * DIM + scol4);
  r.c = *(const float4*)(base + (size_t)(t * 64 + srow + 32) * DIM + scol4);
  r.d = *(const float4*)(base + (size_t)(t * 64 + srow + 48) * DIM + scol4);
  return r;
}
__device__ __forceinline__ void store_t4(float* lds, T4 s, int srow, int scol4) {
  *(float4*)(lds + (srow +  0) * 68 + scol4) = s.a;
  *(float4*)(lds + (srow + 16) * 68 + scol4) = s.b;
  *(float4*)(lds + (srow + 32) * 68 + scol4) = s.c;
  *(float4*)(lds + (srow + 48) * 68 + scol4) = s.d;
}

// ---------------------------------------------------------------- pooling
__global__ __launch_bounds__(256) void pool_kernel(
    const float* __restrict__ q, const float* __restrict__ k,
    float* __restrict__ ql_s, float* __restrict__ kl) {
  int b = blockIdx.x >> 6, n = blockIdx.x & 63;
  int tid = threadIdx.x;
  int rg = tid >> 4, d4 = tid & 15;
  const float* qb = q + ((size_t)b * SLEN + (size_t)n * SEG) * DIM;
  const float* kb = k + ((size_t)b * SLEN + (size_t)n * SEG) * DIM;
  float4 aq = make_float4(0.f, 0.f, 0.f, 0.f);
  float4 ak = make_float4(0.f, 0.f, 0.f, 0.f);
  #pragma unroll
  for (int j = 0; j < 8; ++j) {
    int r = rg * 8 + j;
    float4 t = *(const float4*)(qb + r * DIM + 4 * d4);
    aq.x += t.x; aq.y += t.y; aq.z += t.z; aq.w += t.w;
    float4 u = *(const float4*)(kb + r * DIM + 4 * d4);
    ak.x += u.x; ak.y += u.y; ak.z += u.z; ak.w += u.w;
  }
  __shared__ float4 sq[256], sk[256];
  sq[tid] = aq; sk[tid] = ak;
  __syncthreads();
  #pragma unroll
  for (int off = 128; off >= 16; off >>= 1) {
    if (tid < off) {
      float4 a = sq[tid], bb = sq[tid + off];
      sq[tid] = make_float4(a.x + bb.x, a.y + bb.y, a.z + bb.z, a.w + bb.w);
      float4 c2 = sk[tid], d2 = sk[tid + off];
      sk[tid] = make_float4(c2.x + d2.x, c2.y + d2.y, c2.z + d2.z, c2.w + d2.w);
    }
    __syncthreads();
  }
  if (tid < 16) {
    float4 a = sq[tid], bb = sk[tid];
    size_t o = ((size_t)b * M + n) * DIM + 4 * tid;
    const float qs = 0.125f / 128.f, ks = 1.f / 128.f;
    *(float4*)(ql_s + o) = make_float4(a.x * qs, a.y * qs, a.z * qs, a.w * qs);
    *(float4*)(kl + o) = make_float4(bb.x * ks, bb.y * ks, bb.z * ks, bb.w * ks);
  }
}

// ---------------- phase B (kernel_3 split partials) + pinv, shared 53 KB LDS
__global__ __launch_bounds__(256) void phaseB_pinv_kernel(
    const float* __restrict__ k, const float* __restrict__ v,
    const float* __restrict__ ql_s, const float* __restrict__ klg,
    float* num_p, float* den_p, float* k2inv_g, float* k2_g) {
  __shared__ float smem[13312];  // 53248 B -> 3 blocks/CU
  int tid = threadIdx.x;
  int r0 = (tid >> 4) << 2, c0 = (tid & 15) << 2;
  int srow = tid >> 4, scol4 = (tid & 15) << 2;

  if (blockIdx.x >= NB) {
    // ---------------- phase B ----------------
    int blk = blockIdx.x - NB;
    int b = blk >> 5, sp = blk & 31;
    float* qlT = smem;            // [64 d][68 m]  (ql_s transposed)
    float* kv = smem + 4352;      // [64 s][68]    (k tile, then v tile)
    float* Es = smem + 8704;      // [64 s][68 m]
    float* dredF = smem + 13056;  // [4][64]

    #pragma unroll
    for (int i = 0; i < 16; ++i) {
      int e = tid + 256 * i;
      qlT[(e & 63) * 68 + (e >> 6)] = ql_s[(size_t)b * 4096 + e];
    }
    int m_den = tid & 63, qg = tid >> 6;
    float den_acc = 0.f;
    float cN[4][4];
    #pragma unroll
    for (int i = 0; i < 4; ++i)
      #pragma unroll
      for (int j = 0; j < 4; ++j) cN[i][j] = 0.f;

    const float* kbase = k + ((size_t)b * SLEN + (size_t)sp * CHUNK) * DIM;
    const float* vbase = v + ((size_t)b * SLEN + (size_t)sp * CHUNK) * DIM;

    // prologue prefetch: k first, then v (k-use waits on fewer loads)
    T4 kr = load_t4(kbase, 0, srow, scol4);
    T4 vr = load_t4(vbase, 0, srow, scol4);

    #pragma unroll
    for (int sc = 0; sc < TILES; ++sc) {
      store_t4(kv, kr, srow, scol4);  // waits only on k loads
      __syncthreads();  // A: k tile (and prologue qlT) visible
      // score GEMM: E[s][m] = exp(k[s] . ql_s[m])
      float c[4][4];
      #pragma unroll
      for (int i = 0; i < 4; ++i)
        #pragma unroll
        for (int j = 0; j < 4; ++j) c[i][j] = 0.f;
      mm_p1(kv, 68, qlT, 68, r0, c0, c);
      #pragma unroll
      for (int i = 0; i < 4; ++i)
        #pragma unroll
        for (int j = 0; j < 4; ++j) c[i][j] = __expf(c[i][j]);
      __syncthreads();  // B: k reads done
      // v tile (arrived under the GEMM) over kv; write E
      store_t4(kv, vr, srow, scol4);
      #pragma unroll
      for (int i = 0; i < 4; ++i)
        *(float4*)(Es + (r0 + i) * 68 + c0) =
            make_float4(c[i][0], c[i][1], c[i][2], c[i][3]);
      // prefetch NEXT k/v: den+PV phase (~1500 cyc) covers the HBM latency
      if (sc < TILES - 1) {
        kr = load_t4(kbase, sc + 1, srow, scol4);
        vr = load_t4(vbase, sc + 1, srow, scol4);
      }
      __syncthreads();  // C: v + E visible
      // den partial + num outer product
      #pragma unroll
      for (int t = 0; t < 16; ++t) den_acc += Es[(qg * 16 + t) * 68 + m_den];
      mm_p2(Es, 68, kv, 68, r0, c0, cN);
      __syncthreads();  // D: Es/kv reads done before next overwrite
    }
    dredF[qg * 64 + m_den] = den_acc;
    __syncthreads();
    if (tid < 64)
      den_p[((size_t)b * SPLITS + sp) * 64 + tid] =
          dredF[tid] + dredF[64 + tid] + dredF[128 + tid] + dredF[192 + tid];
    float* np = num_p + ((size_t)b * SPLITS + sp) * 4096;
    #pragma unroll
    for (int i = 0; i < 4; ++i)
      *(float4*)(np + (size_t)(r0 + i) * 64 + c0) =
          make_float4(cN[i][0], cN[i][1], cN[i][2], cN[i][3]);
  } else {
    // ---------------- pinv (3 buffers; K2 kept in global) ----------------
    int b = blockIdx.x;
    float* b1 = smem;            // ql rows, then V
    float* b2 = smem + 4352;     // klT, then A1=K*V
    float* b3 = smem + 8704;     // rowsum partials, K2 copy, then NS temp
    float* red = smem + 13056;   // [64+]
    float* k2b = k2_g + (size_t)b * 4096;

    #pragma unroll
    for (int i = 0; i < 4; ++i) {
      int idx = tid + 256 * i;
      int s = idx >> 4, j = idx & 15;
      *(float4*)(b1 + s * 68 + 4 * j) =
          *(const float4*)(ql_s + (size_t)b * 4096 + (size_t)s * 64 + 4 * j);
    }
    #pragma unroll
    for (int i = 0; i < 16; ++i) {
      int e = tid + 256 * i;
      b2[(e & 63) * 68 + (e >> 6)] = klg[(size_t)b * 4096 + e];
    }
    __syncthreads();
    // kernel_2 scores
    float c[4][4];
    #pragma unroll
    for (int i = 0; i < 4; ++i)
      #pragma unroll
      for (int j = 0; j < 4; ++j) c[i][j] = 0.f;
    mm_p1(b1, 68, b2, 68, r0, c0, c);
    #pragma unroll
    for (int i = 0; i < 4; ++i) {
      float pr = 0.f;
      #pragma unroll
      for (int j = 0; j < 4; ++j) { c[i][j] = __expf(c[i][j]); pr += c[i][j]; }
      b3[(r0 + i) * 16 + (tid & 15)] = pr;
    }
    __syncthreads();
    if (tid < 64) {
      float rs = 0.f;
      #pragma unroll
      for (int g = 0; g < 16; ++g) rs += b3[tid * 16 + g];
      red[tid] = 1.f / rs;
    }
    __syncthreads();
    // normalize -> K2 (global + LDS b3)
    #pragma unroll
    for (int i = 0; i < 4; ++i) {
      float inv = red[r0 + i];
      #pragma unroll
      for (int j = 0; j < 4; ++j) c[i][j] *= inv;
      float4 val = make_float4(c[i][0], c[i][1], c[i][2], c[i][3]);
      *(float4*)(k2b + (size_t)(r0 + i) * 64 + c0) = val;
      *(float4*)(b3 + (r0 + i) * 68 + c0) = val;
    }
    __syncthreads();
    // init scale: 1/max_m colsum
    if (tid < 64) {
      float cs = 0.f;
      #pragma unroll 8
      for (int n2 = 0; n2 < 64; ++n2) cs += b3[n2 * 68 + tid];
      float mx = cs;
      #pragma unroll
      for (int off = 1; off < 64; off <<= 1) mx = fmaxf(mx, __shfl_xor(mx, off));
      red[0] = 1.f / mx;
    }
    __syncthreads();
    float iscale = red[0];
    // V = iscale * K2^T -> b1 (ql dead)
    #pragma unroll
    for (int i = 0; i < 16; ++i) {
      int e = tid + 256 * i;
      int r = e >> 6, cc = e & 63;
      b1[r * 68 + cc] = b3[cc * 68 + r] * iscale;
    }
    __syncthreads();

    for (int it = 0; it < 6; ++it) {
      // A1 = K2 @ V -> b2
      #pragma unroll
      for (int i = 0; i < 4; ++i)
        #pragma unroll
        for (int j = 0; j < 4; ++j) c[i][j] = 0.f;
      mm_p1(k2b, 64, b1, 68, r0, c0, c);
      #pragma unroll
      for (int i = 0; i < 4; ++i)
        *(float4*)(b2 + (r0 + i) * 68 + c0) =
            make_float4(c[i][0], c[i][1], c[i][2], c[i][3]);
      __syncthreads();
      // T = A1 @ (7I - A1) -> b3
      #pragma unroll
      for (int i = 0; i < 4; ++i)
        #pragma unroll
        for (int j = 0; j < 4; ++j) c[i][j] = 0.f;
      mm_p1_tf(b2, 68, b2, 68, 7.f, r0, c0, c);
      #pragma unroll
      for (int i = 0; i < 4; ++i)
        *(float4*)(b3 + (r0 + i) * 68 + c0) =
            make_float4(c[i][0], c[i][1], c[i][2], c[i][3]);
      __syncthreads();
      // R = A1 @ (15I - T) -> b3 in place (barrier before write)
      #pragma unroll
      for (int i = 0; i < 4; ++i)
        #pragma unroll
        for (int j = 0; j < 4; ++j) c[i][j] = 0.f;
      mm_p1_tf(b2, 68, b3, 68, 15.f, r0, c0, c);
      __syncthreads();
      #pragma unroll
      for (int i = 0; i < 4; ++i)
        *(float4*)(b3 + (r0 + i) * 68 + c0) =
            make_float4(c[i][0], c[i][1], c[i][2], c[i][3]);
      __syncthreads();
      // V = 0.25 * V @ (13I - R) -> b1 in place
      #pragma unroll
      for (int i = 0; i < 4; ++i)
        #pragma unroll
        for (int j = 0; j < 4; ++j) c[i][j] = 0.f;
      mm_p1_tf(b1, 68, b3, 68, 13.f, r0, c0, c);
      __syncthreads();
      #pragma unroll
      for (int i = 0; i < 4; ++i)
        *(float4*)(b1 + (r0 + i) * 68 + c0) = make_float4(
            0.25f * c[i][0], 0.25f * c[i][1], 0.25f * c[i][2], 0.25f * c[i][3]);
      __syncthreads();
    }
    #pragma unroll
    for (int i = 0; i < 16; ++i) {
      int e = tid + 256 * i;
      k2inv_g[(size_t)b * 4096 + e] = b1[(e >> 6) * 68 + (e & 63)];
    }
  }
}

// ------------------------------------------------ reduce split partials -> k3
__global__ __launch_bounds__(256) void combine1_kernel(
    const float* __restrict__ num_p, const float* __restrict__ den_p,
    float* __restrict__ k3) {
  int b = blockIdx.x >> 3, slice = blockIdx.x & 7;
  int tid = threadIdx.x;
  int e0 = slice * 512 + tid * 2;
  float a0 = 0.f, a1 = 0.f;
  for (int sp = 0; sp < SPLITS; ++sp) {
    float2 t = *(const float2*)(num_p + ((size_t)b * SPLITS + sp) * 4096 + e0);
    a0 += t.x; a1 += t.y;
  }
  int m = e0 >> 6;
  float dsum = 0.f;
  for (int sp = 0; sp < SPLITS; ++sp)
    dsum += den_p[((size_t)b * SPLITS + sp) * 64 + m];
  float dinv = 1.f / dsum;
  *(float2*)(k3 + (size_t)b * 4096 + e0) = make_float2(a0 * dinv, a1 * dinv);
}

// ------------------------------------------------------ W = k2inv @ k3
__global__ __launch_bounds__(256) void combine2_kernel(
    const float* __restrict__ k2inv, const float* __restrict__ k3,
    float* __restrict__ Wm) {
  __shared__ float A[4352], Bm[4352];
  int b = blockIdx.x, tid = threadIdx.x;
  int r0 = (tid >> 4) << 2, c0 = (tid & 15) << 2;
  #pragma unroll
  for (int i = 0; i < 4; ++i) {
    int idx = tid + 256 * i;
    int s = idx >> 4, j = idx & 15;
    *(float4*)(A + s * 68 + 4 * j) =
        *(const float4*)(k2inv + (size_t)b * 4096 + (size_t)s * 64 + 4 * j);
    *(float4*)(Bm + s * 68 + 4 * j) =
        *(const float4*)(k3 + (size_t)b * 4096 + (size_t)s * 64 + 4 * j);
  }
  __syncthreads();
  float c[4][4];
  #pragma unroll
  for (int i = 0; i < 4; ++i)
    #pragma unroll
    for (int j = 0; j < 4; ++j) c[i][j] = 0.f;
  mm_p1(A, 68, Bm, 68, r0, c0, c);
  #pragma unroll
  for (int i = 0; i < 4; ++i)
    *(float4*)(Wm + (size_t)b * 4096 + (size_t)(r0 + i) * 64 + c0) =
        make_float4(c[i][0], c[i][1], c[i][2], c[i][3]);
}

// --------------------------- final: x = softmax(q*scale @ kl^T) @ W, fused
// Row ownership: group g (tids 16g..16g+15) reads q rows 4g..4g+3 as the
// scores A-operand and overwrites exactly those rows with E -> no barrier
// between E-write and the out-GEMM (same-wave, in-order DS). den via shfl_xor.
__global__ __launch_bounds__(256) void final_kernel(
    const float* __restrict__ q, const float* __restrict__ klg,
    const float* __restrict__ Wm, float* __restrict__ out) {
  __shared__ float smem[12800];  // 51200 B -> 3 blocks/CU
  float* klT = smem;             // [64 d][68 m]
  float* Wl = smem + 4352;       // [64 m][64 d]
  float* Es = smem + 8448;       // q tile, then E tile [64 r][68]
  int b = blockIdx.x >> 5, rb = blockIdx.x & 31;
  int tid = threadIdx.x;
  int r0 = (tid >> 4) << 2, c0 = (tid & 15) << 2;
  int srow = tid >> 4, scol4 = (tid & 15) << 2;

  #pragma unroll
  for (int i = 0; i < 16; ++i) {
    int e = tid + 256 * i;
    klT[(e & 63) * 68 + (e >> 6)] = klg[(size_t)b * 4096 + e];
  }
  #pragma unroll
  for (int i = 0; i < 4; ++i) {
    int idx = tid + 256 * i;
    *(float4*)(Wl + idx * 4) = *(const float4*)(Wm + (size_t)b * 4096 + idx * 4);
  }

  const float* qbase = q + ((size_t)b * SLEN + (size_t)rb * FROWS) * DIM;
  float* obase = out + ((size_t)b * SLEN + (size_t)rb * FROWS) * DIM;
  T4 qr = load_t4(qbase, 0, srow, scol4);

  #pragma unroll
  for (int sc = 0; sc < FTILES; ++sc) {
    // stage q tile (scaled)
    {
      float4 t;
      t = qr.a; *(float4*)(Es + (srow +  0) * 68 + scol4) =
          make_float4(t.x * 0.125f, t.y * 0.125f, t.z * 0.125f, t.w * 0.125f);
      t = qr.b; *(float4*)(Es + (srow + 16) * 68 + scol4) =
          make_float4(t.x * 0.125f, t.y * 0.125f, t.z * 0.125f, t.w * 0.125f);
      t = qr.c; *(float4*)(Es + (srow + 32) * 68 + scol4) =
          make_float4(t.x * 0.125f, t.y * 0.125f, t.z * 0.125f, t.w * 0.125f);
      t = qr.d; *(float4*)(Es + (srow + 48) * 68 + scol4) =
          make_float4(t.x * 0.125f, t.y * 0.125f, t.z * 0.125f, t.w * 0.125f);
    }
    __syncthreads();  // A: q tile (and prologue klT/Wl) visible
    // scores
    float c[4][4];
    #pragma unroll
    for (int i = 0; i < 4; ++i)
      #pragma unroll
      for (int j = 0; j < 4; ++j) c[i][j] = 0.f;
    mm_p1(Es, 68, klT, 68, r0, c0, c);
    #pragma unroll
    for (int i = 0; i < 4; ++i)
      #pragma unroll
      for (int j = 0; j < 4; ++j) c[i][j] = __expf(c[i][j]);
    // row denominators: 16-lane group shuffle reduce (no LDS, no barrier)
    float inv[4];
    #pragma unroll
    for (int i = 0; i < 4; ++i) {
      float s = (c[i][0] + c[i][1]) + (c[i][2] + c[i][3]);
      s += __shfl_xor(s, 1);
      s += __shfl_xor(s, 2);
      s += __shfl_xor(s, 4);
      s += __shfl_xor(s, 8);
      inv[i] = 1.f / s;
    }
    // write E over own q rows (same-wave rows; no barrier needed)
    #pragma unroll
    for (int i = 0; i < 4; ++i)
      *(float4*)(Es + (r0 + i) * 68 + c0) =
          make_float4(c[i][0], c[i][1], c[i][2], c[i][3]);
    // prefetch next q tile: out-GEMM (~1024 fma) covers the HBM latency
    if (sc < FTILES - 1) qr = load_t4(qbase, sc + 1, srow, scol4);
    // out = (E @ W) * inv
    float c3[4][4];
    #pragma unroll
    for (int i = 0; i < 4; ++i)
      #pragma unroll
      for (int j = 0; j < 4; ++j) c3[i][j] = 0.f;
    mm_p1(Es, 68, Wl, 64, r0, c0, c3);
    #pragma unroll
    for (int i = 0; i < 4; ++i)
      *(float4*)(obase + (size_t)(sc * 64 + r0 + i) * 64 + c0) = make_float4(
          c3[i][0] * inv[i], c3[i][1] * inv[i], c3[i][2] * inv[i],
          c3[i][3] * inv[i]);
    __syncthreads();  // C: Es reads done before next stage-write
  }
}

// ----------------------------------------------------------------- launcher
extern "C" void kernel_launch(void* const* d_in, const int* in_sizes, int n_in,
                              void* d_out, int out_size, void* d_ws, size_t ws_size,
                              hipStream_t stream) {
  (void)in_sizes; (void)n_in; (void)out_size; (void)ws_size;
  const float* q = (const float*)d_in[0];
  const float* k = (const float*)d_in[1];
  const float* v = (const float*)d_in[2];
  float* out = (float*)d_out;
  float* ws = (float*)d_ws;

  float* ql_s = ws;
  float* kl = ws + 131072;
  float* k2inv = ws + 262144;
  float* Wm = ws + 393216;  // pinv K2 scratch, then combine2 output
  float* k3 = ws + 524288;
  float* den_p = ws + 655360;
  float* num_p = ws + 720896;

  pool_kernel<<<NB * 64, 256, 0, stream>>>(q, k, ql_s, kl);
  // pinv blocks 0..31 dispatch first and run concurrently with phase B
  phaseB_pinv_kernel<<<NB + NB * SPLITS, 256, 0, stream>>>(
      k, v, ql_s, kl, num_p, den_p, k2inv, Wm);
  combine1_kernel<<<NB * 8, 256, 0, stream>>>(num_p, den_p, k3);
  combine2_kernel<<<NB, 256, 0, stream>>>(k2inv, k3, Wm);
  final_kernel<<<NB * 32, 256, 0, stream>>>(q, kl, Wm, out);
}